// Round 1
// baseline (543.314 us; speedup 1.0000x reference)
//
#include <hip/hip_runtime.h>

#define D 64
#define NITER 14

// One block (128 threads = 2 waves) per batch.
// wave 0 owns k1 / A1, wave 1 owns k2 / A2. Lane i owns row i.
__global__ __launch_bounds__(128) void glrk_kernel(
    const float* __restrict__ A1, const float* __restrict__ A2,
    const float* __restrict__ y0, const float* __restrict__ hp,
    float* __restrict__ outy, float* __restrict__ oA1, float* __restrict__ oA2)
{
    const int b = blockIdx.x;
    const int wave = threadIdx.x >> 6;
    const int lane = threadIdx.x & 63;

    const float h = *hp;
    // Butcher tableau: A11=A22=1/4, A12=1/4-sqrt(3)/6, A21=1/4+sqrt(3)/6
    const float ca = (wave == 0) ? 0.25f : (0.25f + 0.28867513459481287f);
    const float cb = (wave == 0) ? (0.25f - 0.28867513459481287f) : 0.25f;

    __shared__ float s_y0[D];
    __shared__ float s_k[2][D];
    __shared__ float s_v[2][D];

    const size_t moff = (size_t)b * (D * D);
    const float4* src = (const float4*)((wave ? A2 : A1) + moff) + (size_t)lane * (D / 4);
    float4*       dst = (float4*)((wave ? oA2 : oA1) + moff) + (size_t)lane * (D / 4);

    // Load my row into registers; stream the copy to the output at the same time.
    float row[D];
#pragma unroll
    for (int c = 0; c < D / 4; ++c) {
        float4 t = src[c];
        dst[c] = t;
        row[4 * c + 0] = t.x;
        row[4 * c + 1] = t.y;
        row[4 * c + 2] = t.z;
        row[4 * c + 3] = t.w;
    }

    if (wave == 0) s_y0[lane] = y0[(size_t)b * D + lane];
    s_k[wave][lane] = 0.0f;
    __syncthreads();

    const float4* vv = (const float4*)s_v[wave];
    for (int it = 0; it < NITER; ++it) {
        // v_w = y0 + h*(ca*k1 + cb*k2)   (elementwise, lane = element)
        float v = fmaf(h, fmaf(ca, s_k[0][lane], cb * s_k[1][lane]), s_y0[lane]);
        s_v[wave][lane] = v;
        __syncthreads();

        // k_w[i] = dot(A_w row i, v_w)  — vv[c] is a wave-uniform LDS broadcast
        float a0 = 0.f, a1 = 0.f, a2 = 0.f, a3 = 0.f;
#pragma unroll
        for (int c = 0; c < D / 4; ++c) {
            float4 u = vv[c];
            a0 = fmaf(row[4 * c + 0], u.x, a0);
            a1 = fmaf(row[4 * c + 1], u.y, a1);
            a2 = fmaf(row[4 * c + 2], u.z, a2);
            a3 = fmaf(row[4 * c + 3], u.w, a3);
        }
        s_k[wave][lane] = (a0 + a1) + (a2 + a3);
        __syncthreads();
    }

    if (wave == 0) {
        // y_next = y0 + h*(0.5*k1 + 0.5*k2)
        float yn = fmaf(h, 0.5f * (s_k[0][lane] + s_k[1][lane]), s_y0[lane]);
        outy[(size_t)b * D + lane] = yn;
    }
}

extern "C" void kernel_launch(void* const* d_in, const int* in_sizes, int n_in,
                              void* d_out, int out_size, void* d_ws, size_t ws_size,
                              hipStream_t stream) {
    const float* A1 = (const float*)d_in[0];
    const float* A2 = (const float*)d_in[1];
    const float* y0 = (const float*)d_in[2];
    const float* hp = (const float*)d_in[3];

    const int B = in_sizes[2] / D;  // y0 is (B, D)

    float* outy = (float*)d_out;                    // B*D
    float* oA1  = outy + (size_t)B * D;             // B*D*D
    float* oA2  = oA1 + (size_t)B * D * D;          // B*D*D

    glrk_kernel<<<B, 128, 0, stream>>>(A1, A2, y0, hp, outy, oA1, oA2);
}

// Round 2
// 444.465 us; speedup vs baseline: 1.2224x; 1.2224x over previous
//
#include <hip/hip_runtime.h>

#define D 64
#define RS 68          // LDS row stride (floats): +4 pad breaks 64-stride bank conflicts
#define NITER 14

// One block (128 threads = 2 waves) per batch.
// wave 0 owns k1 / A1, wave 1 owns k2 / A2. Lane i owns row i (held in VGPRs).
__global__ __launch_bounds__(128, 4) void glrk_kernel(
    const float* __restrict__ A1, const float* __restrict__ A2,
    const float* __restrict__ y0, const float* __restrict__ hp,
    float* __restrict__ outy, float* __restrict__ oA1, float* __restrict__ oA2)
{
    const int b    = blockIdx.x;
    const int t    = threadIdx.x;   // 0..127
    const int wave = t >> 6;
    const int lane = t & 63;

    __shared__ float sA[D * RS];    // 17408 B staging tile
    __shared__ float s_y0[D];
    __shared__ float s_k[2][D];
    __shared__ float s_v[2][D];

    const float h  = *hp;
    const float ca = (wave == 0) ? 0.25f                 : 0.5386751345948129f;   // 1/4 + sqrt3/6
    const float cb = (wave == 0) ? -0.03867513459481287f : 0.25f;                 // 1/4 - sqrt3/6

    const size_t moff = (size_t)b * (D * D);
    float row[D];

    // ---- Stage A1: coalesced global read + coalesced output copy + LDS stage
    {
        const float4* src = (const float4*)(A1 + moff);
        float4*       dst = (float4*)(oA1 + moff);
#pragma unroll
        for (int k = 0; k < 8; ++k) {
            const int f4 = t + k * 128;          // float4 index in 64x64 matrix
            float4 v = src[f4];
            dst[f4] = v;
            const int f = f4 * 4;
            const int r = f >> 6, c = f & 63;
            *(float4*)&sA[r * RS + c] = v;
        }
    }
    if (wave == 0) s_y0[lane] = y0[(size_t)b * D + lane];
    s_k[wave][lane] = 0.0f;
    __syncthreads();

    if (wave == 0) {
#pragma unroll
        for (int c = 0; c < D; c += 4) {
            float4 v = *(const float4*)&sA[lane * RS + c];
            row[c] = v.x; row[c + 1] = v.y; row[c + 2] = v.z; row[c + 3] = v.w;
        }
    }
    __syncthreads();

    // ---- Stage A2 (reuse the same LDS tile)
    {
        const float4* src = (const float4*)(A2 + moff);
        float4*       dst = (float4*)(oA2 + moff);
#pragma unroll
        for (int k = 0; k < 8; ++k) {
            const int f4 = t + k * 128;
            float4 v = src[f4];
            dst[f4] = v;
            const int f = f4 * 4;
            const int r = f >> 6, c = f & 63;
            *(float4*)&sA[r * RS + c] = v;
        }
    }
    __syncthreads();

    if (wave == 1) {
#pragma unroll
        for (int c = 0; c < D; c += 4) {
            float4 v = *(const float4*)&sA[lane * RS + c];
            row[c] = v.x; row[c + 1] = v.y; row[c + 2] = v.z; row[c + 3] = v.w;
        }
    }
    // sA is not touched again; no barrier needed before the loop
    // (s_y0 / s_k zero-init were published at the first barrier).

    const float4* vv = (const float4*)s_v[wave];
    for (int it = 0; it < NITER; ++it) {
        // v_w = y0 + h*(ca*k1 + cb*k2)   (elementwise, lane = element)
        float v = fmaf(h, fmaf(ca, s_k[0][lane], cb * s_k[1][lane]), s_y0[lane]);
        s_v[wave][lane] = v;
        __syncthreads();

        // k_w[i] = dot(A_w row i, v_w)  — vv[c] is a wave-uniform LDS broadcast
        float a0 = 0.f, a1 = 0.f, a2 = 0.f, a3 = 0.f;
#pragma unroll
        for (int c = 0; c < D / 4; ++c) {
            float4 u = vv[c];
            a0 = fmaf(row[4 * c + 0], u.x, a0);
            a1 = fmaf(row[4 * c + 1], u.y, a1);
            a2 = fmaf(row[4 * c + 2], u.z, a2);
            a3 = fmaf(row[4 * c + 3], u.w, a3);
        }
        s_k[wave][lane] = (a0 + a1) + (a2 + a3);
        __syncthreads();
    }

    if (wave == 0) {
        // y_next = y0 + h*(0.5*k1 + 0.5*k2)
        float yn = fmaf(h, 0.5f * (s_k[0][lane] + s_k[1][lane]), s_y0[lane]);
        outy[(size_t)b * D + lane] = yn;
    }
}

extern "C" void kernel_launch(void* const* d_in, const int* in_sizes, int n_in,
                              void* d_out, int out_size, void* d_ws, size_t ws_size,
                              hipStream_t stream) {
    const float* A1 = (const float*)d_in[0];
    const float* A2 = (const float*)d_in[1];
    const float* y0 = (const float*)d_in[2];
    const float* hp = (const float*)d_in[3];

    const int B = in_sizes[2] / D;  // y0 is (B, D)

    float* outy = (float*)d_out;            // B*D
    float* oA1  = outy + (size_t)B * D;     // B*D*D
    float* oA2  = oA1 + (size_t)B * D * D;  // B*D*D

    glrk_kernel<<<B, 128, 0, stream>>>(A1, A2, y0, hp, outy, oA1, oA2);
}